// Round 12
// baseline (303.754 us; speedup 1.0000x reference)
//
#include <hip/hip_runtime.h>
#include <hip/hip_bf16.h>

#define BB 16
#define NN 1024
#define DD 256
#define FF_ 128
#define LL 2
#define RR 2
#define DF 384
#define MM (BB*NN)
#define NPROJ 1280
#define PK 768            // POUT row stride (Q:0..255, K0:256..511, K1:512..767)
#define CSC 0.09016844f   // (1/16) * log2(e), folded into WQ at prep

typedef __attribute__((ext_vector_type(8))) short s16x8;
typedef __attribute__((ext_vector_type(4))) float f32x4;
typedef __attribute__((ext_vector_type(16))) float f32x16;
typedef __attribute__((ext_vector_type(2))) unsigned int u32x2;
typedef __attribute__((ext_vector_type(4))) unsigned int u32x4;
typedef __attribute__((ext_vector_type(4))) unsigned short us16x4;

__device__ __forceinline__ unsigned short f2bf(float f){
  unsigned u = __builtin_bit_cast(unsigned, f);
  u += 0x7fff + ((u >> 16) & 1);
  return (unsigned short)(u >> 16);
}

__device__ __forceinline__ void gload16(const void* g, void* l){
  __builtin_amdgcn_global_load_lds(
      (const __attribute__((address_space(1))) unsigned int*)g,
      (__attribute__((address_space(3))) unsigned int*)l, 16, 0, 0);
}

#define MFMA16(a,b,c) __builtin_amdgcn_mfma_f32_16x16x32_bf16((a),(b),(c),0,0,0)
#define MFMA32(a,b,c) __builtin_amdgcn_mfma_f32_32x32x16_bf16((a),(b),(c),0,0,0)

// ---------------- adj -> bitmask (R,B,N, 16 x u64) ----------------
__global__ __launch_bounds__(256) void pack_adj(const int* __restrict__ adj,
                                                unsigned long long* __restrict__ bits){
  int w = threadIdx.x >> 6, lane = threadIdx.x & 63;
  size_t row = (size_t)blockIdx.x * 4 + w;
  const int* a = adj + row * NN;
  unsigned long long* brow = bits + row * 16;
  #pragma unroll
  for (int j = 0; j < 16; ++j){
    unsigned long long m = __ballot(a[j*64 + lane] != 0);
    if (lane == 0) brow[j] = m;
  }
}

// ---------------- one-shot prep: weights, biases, x1, hbf ----------------
#define PREP_WT   3840
#define PREP_WTF  1024
#define PREP_BALL 10
#define PREP_X1   16
#define PREP_H    2048
#define PREP_TOT  (PREP_WT+PREP_WTF+PREP_BALL+PREP_X1+PREP_H)

__global__ __launch_bounds__(256) void prep(
    const float* __restrict__ node, const float* __restrict__ inx,
    const float* __restrict__ WQi_w, const float* __restrict__ WQi_b,
    const float* __restrict__ WQ_w, const float* __restrict__ WK_w,
    const float* __restrict__ WV_w, const float* __restrict__ WQ_b,
    const float* __restrict__ WK_b, const float* __restrict__ WV_b,
    const float* __restrict__ WF_w,
    unsigned short* __restrict__ wtall, unsigned short* __restrict__ wtf,
    float* __restrict__ ball, unsigned short* __restrict__ x1bf,
    unsigned short* __restrict__ hbf){
  int bid = blockIdx.x, t = threadIdx.x;
  if (bid < PREP_WT){
    int o = bid*256 + t;                       // < 2*1280*384
    int l = o / (NPROJ*DF); int oo = o - l*(NPROJ*DF);
    int n = oo / DF, k = oo - n*DF;
    const float* WQ = WQ_w + (size_t)l*DF*256;
    const float* WK = WK_w + (size_t)l*RR*DF*256;
    const float* WV = WV_w + (size_t)l*RR*DF*256;
    float v;
    if (n < 256)      v = WQ[(size_t)k*256 + n] * CSC;   // fold attn scale into Q
    else if (n < 768) v = WK[(size_t)((n-256)>>8)*(DF*256) + (size_t)k*256 + ((n-256)&255)];
    else              v = WV[(size_t)((n-768)>>8)*(DF*256) + (size_t)k*256 + ((n-768)&255)];
    wtall[o] = f2bf(v);
  } else if (bid < PREP_WT + PREP_WTF){
    int o = (bid - PREP_WT)*256 + t;           // < 2*512*256
    int l = o >> 17; int oo = o & 131071;
    int n = oo >> 9, k = oo & 511;
    wtf[o] = f2bf(WF_w[(size_t)l*512*256 + (size_t)k*256 + n]);
  } else if (bid < PREP_WT + PREP_WTF + PREP_BALL){
    int o = (bid - PREP_WT - PREP_WTF)*256 + t;
    if (o < 2*NPROJ){
      int l = o / NPROJ, n = o - l*NPROJ;
      float v = (n < 256) ? WQ_b[l*256 + n] * CSC
              : (n < 768) ? WK_b[(size_t)l*512 + (n-256)]
                          : WV_b[(size_t)l*512 + (n-768)];
      ball[o] = v;
    }
  } else if (bid < PREP_WT + PREP_WTF + PREP_BALL + PREP_X1){
    int o = (bid - PREP_WT - PREP_WTF - PREP_BALL)*256 + t;  // < 4096
    int l = o >> 11, bj = o & 2047;
    int b = bj >> 7, j = bj & 127;
    const float* w = WQi_w + (size_t)l*FF_*FF_;
    float s = WQi_b[l*FF_ + j];
    for (int i = 0; i < FF_; ++i) s += inx[b*FF_ + i] * w[i*FF_ + j];
    x1bf[o] = f2bf(s);
  } else {
    int o = (bid - (PREP_TOT - PREP_H))*256 + t;             // < 524288, 8 elems each
    const float4* src = (const float4*)node + (size_t)o*2;
    float4 a = src[0], c = src[1];
    uint4 pk;
    pk.x = (unsigned)f2bf(a.x) | ((unsigned)f2bf(a.y) << 16);
    pk.y = (unsigned)f2bf(a.z) | ((unsigned)f2bf(a.w) << 16);
    pk.z = (unsigned)f2bf(c.x) | ((unsigned)f2bf(c.y) << 16);
    pk.w = (unsigned)f2bf(c.z) | ((unsigned)f2bf(c.w) << 16);
    *(uint4*)(hbf + (size_t)o*8) = pk;
  }
}

// ------------- big projection GEMM: A=concat(hbf,x1), N=1280, K=384 -------------
// bn<6: POUT row-major (stride 768). bn>=6: V written transposed to vtall.
__global__ __launch_bounds__(256) void gemm_big(const unsigned short* __restrict__ hbf,
    const unsigned short* __restrict__ x1l, const unsigned short* __restrict__ Wt,
    const float* __restrict__ bias, unsigned short* __restrict__ POUT,
    unsigned short* __restrict__ vtall){
  __shared__ unsigned short As[2][128*32];
  __shared__ unsigned short Bs[2][128*32];
  int t = threadIdx.x, lane = t & 63, w = t >> 6;
  int wr = w >> 1, wc = w & 1, l15 = lane & 15, lhi = lane >> 4;
  int bm = blockIdx.x, bn = blockIdx.y, bb = bm >> 3;
  f32x4 acc[4][4];
  #pragma unroll
  for (int m = 0; m < 4; ++m)
    #pragma unroll
    for (int n = 0; n < 4; ++n) acc[m][n] = (f32x4){0.f,0.f,0.f,0.f};

  auto STAGE = [&](int bi, int kk){
    #pragma unroll
    for (int i = 0; i < 2; ++i){
      int base = w*2048 + i*1024;
      int off = base + lane*16;
      int row = off >> 6, cb = off & 63;
      const char* asrc = (kk < 8)
        ? (const char*)hbf + ((size_t)(bm*128 + row)*256 + kk*32)*2 + cb
        : (const char*)x1l + ((size_t)bb*128 + (kk-8)*32)*2 + cb;
      gload16(asrc, (char*)As[bi] + base);
      gload16((const char*)Wt + ((size_t)(bn*128 + row)*DF + kk*32)*2 + cb,
              (char*)Bs[bi] + base);
    }
  };

  STAGE(0, 0);
  __syncthreads();
  for (int kk = 0; kk < 12; ++kk){
    int cur = kk & 1;
    if (kk + 1 < 12) STAGE(cur ^ 1, kk + 1);
    s16x8 af[4], bfr[4];
    #pragma unroll
    for (int m = 0; m < 4; ++m) af[m]  = *(const s16x8*)&As[cur][(wr*64 + m*16 + l15)*32 + lhi*8];
    #pragma unroll
    for (int n = 0; n < 4; ++n) bfr[n] = *(const s16x8*)&Bs[cur][(wc*64 + n*16 + l15)*32 + lhi*8];
    __builtin_amdgcn_s_setprio(1);
    #pragma unroll
    for (int m = 0; m < 4; ++m)
      #pragma unroll
      for (int n = 0; n < 4; ++n)
        acc[m][n] = MFMA16(af[m], bfr[n], acc[m][n]);
    __builtin_amdgcn_s_setprio(0);
    __syncthreads();
  }

  if (bn < 6){
    #pragma unroll
    for (int n = 0; n < 4; ++n){
      int gn = bn*128 + wc*64 + n*16 + l15;
      float bv = bias[gn];
      #pragma unroll
      for (int m = 0; m < 4; ++m){
        int gm = bm*128 + wr*64 + m*16 + lhi*4;
        #pragma unroll
        for (int i = 0; i < 4; ++i)
          POUT[(size_t)(gm + i)*PK + gn] = f2bf(acc[m][n][i] + bv);
      }
    }
  } else {
    #pragma unroll
    for (int n = 0; n < 4; ++n){
      int gn = bn*128 + wc*64 + n*16 + l15;
      float bv = bias[gn];
      int rv = gn - 768;
      int r = rv >> 8, d = rv & 255;
      #pragma unroll
      for (int m = 0; m < 4; ++m){
        int mb = (bm & 7)*128 + wr*64 + m*16 + lhi*4;
        us16x4 pk;
        #pragma unroll
        for (int i = 0; i < 4; ++i) pk[i] = f2bf(acc[m][n][i] + bv);
        *(us16x4*)(vtall + ((size_t)((r*16 + bb)*256 + d))*NN + mb) = pk;
      }
    }
  }
}

// ------------- flash attention v10: attn9 + LDS masks + dual QK chain + VALU trim ----
// grid 256 (XCD-swizzled), block 512 = 4 qsubs x 2 d-halves, dbuf counted vmcnt.
// LDS: K/V dbuf 2x64KB @0/@65536; mask block [kt][row] 16KB @131072.
__global__ __launch_bounds__(512, 1) void attn10(const unsigned short* __restrict__ P,
    const unsigned short* __restrict__ VT, const unsigned long long* __restrict__ bits,
    unsigned short* __restrict__ hc){
  __shared__ char smem[147456];

  int t = threadIdx.x, lane = t & 63, w = t >> 6;
  int h = lane >> 5, l31 = lane & 31;
  int qsub = w >> 1, dh = w & 1;          // q-subtile, d-half
  int F = blockIdx.x;
  int xcd = F & 7, j = F >> 3;
  int qt = j & 7;
  int gidx = xcd*4 + (j >> 3);
  int b = gidx & 15, r = gidx >> 4;

  size_t kcol = 256 + (size_t)r*256;
  const unsigned short* Vb = VT + ((size_t)(r*16 + b))*256*NN;
  int qrow = qt*128 + qsub*32 + l31;

  // Q in registers: 16 B-operand frags (lane = q-col, full D), pre-scaled by CSC
  s16x8 qf[16];
  {
    const unsigned short* qp = P + ((size_t)(b*NN + qrow))*PK + h*8;
    #pragma unroll
    for (int d_ = 0; d_ < 16; ++d_) qf[d_] = *(const s16x8*)(qp + d_*16);
  }

  // stage all masks for this block's 128 q-rows into LDS [kt][row] (transposed)
  {
    const unsigned long long* bb0 = bits + ((size_t)(r*BB + b)*NN + qt*128)*16;
    unsigned long long* ml = (unsigned long long*)(smem + 131072);
    #pragma unroll
    for (int i = 0; i < 4; ++i){
      int idx = t + i*512;                // < 2048
      int kt = idx >> 7, row = idx & 127;
      ml[kt*128 + row] = bb0[(size_t)row*16 + kt];
    }
  }

  f32x16 acc[4];                           // d-half: d in [dh*128, dh*128+128)
  #pragma unroll
  for (int dt = 0; dt < 4; ++dt)
    #pragma unroll
    for (int i = 0; i < 16; ++i) acc[dt][i] = 0.f;
  float mrow = -3e38f, lrow = 0.f;

  // buf base = buf*65536; K at +0 (32KB: [64 k][512B swz]), V at +32768
  auto STAGE = [&](int buf, int kt){
    char* base = smem + buf*65536;
    #pragma unroll
    for (int i = 0; i < 4; ++i){
      int o = i*8192 + t*16;              // [0,32768)
      int kr = o >> 9, cb = o & 511;
      int lcb = cb ^ ((kr & 7) << 4);
      gload16((const char*)P + ((size_t)(b*NN + kt*64 + kr)*PK + kcol)*2 + lcb,
              base + o);
    }
    #pragma unroll
    for (int i = 0; i < 4; ++i){
      int o = i*8192 + t*16;
      int vr = o >> 7, cb = o & 127;
      int lcb = cb ^ ((vr & 7) << 4);
      gload16((const char*)Vb + ((size_t)vr*NN + kt*64)*2 + lcb,
              base + 32768 + o);
    }
  };

  STAGE(0, 0);
  __syncthreads();                         // drains Q/mask reads + ds_writes + stage0

  for (int kt = 0; kt < 16; ++kt){
    int cur = kt & 1;
    if (kt + 1 < 16){
      STAGE(cur ^ 1, kt + 1);
      asm volatile("s_waitcnt vmcnt(8)" ::: "memory");
    } else {
      asm volatile("s_waitcnt vmcnt(0)" ::: "memory");
    }
    __builtin_amdgcn_s_barrier();          // cur tiles ready in all waves
    __builtin_amdgcn_sched_barrier(0);

    // mask via LDS (lgkm domain; latency hides under QK)
    unsigned long long mwv64 = *(const unsigned long long*)
        (smem + 131072 + kt*1024 + (qsub*32 + l31)*8);

    const char* Kc = smem + cur*65536;
    const char* Vc = smem + cur*65536 + 32768;

    // QK: dual independent chains over both 32-k subtiles, D=256
    f32x16 st0, st1;
    #pragma unroll
    for (int i = 0; i < 16; ++i){ st0[i] = 0.f; st1[i] = 0.f; }
    int swzk = (l31 & 7) << 4;
    const char* kb0 = Kc + l31*512;
    const char* kb1 = Kc + (32 + l31)*512;
    #pragma unroll
    for (int d_ = 0; d_ < 16; ++d_){
      int co = (d_*32 + h*16) ^ swzk;
      s16x8 kf0 = *(const s16x8*)(kb0 + co);
      s16x8 kf1 = *(const s16x8*)(kb1 + co);
      st0 = MFMA32(kf0, qf[d_], st0);
      st1 = MFMA32(kf1, qf[d_], st1);
    }

    // per-subtile: mask -> online softmax -> pack -> PV (s1's VALU overlaps s0's PV)
    auto PROC = [&](f32x16 st, unsigned mw, int vcol){
      #pragma unroll
      for (int rr = 0; rr < 16; ++rr){
        int kb = (rr & 3) + 8*(rr >> 2) + 4*h;
        st[rr] = ((mw >> kb) & 1u) ? st[rr] : -1.443e9f;
      }
      float t8[8];
      #pragma unroll
      for (int p = 0; p < 8; ++p) t8[p] = fmaxf(st[p], st[p+8]);
      #pragma unroll
      for (int p = 0; p < 4; ++p) t8[p] = fmaxf(t8[p], t8[p+4]);
      float tm = fmaxf(fmaxf(t8[0], t8[1]), fmaxf(t8[2], t8[3]));
      tm = fmaxf(tm, __shfl_xor(tm, 32));
      if (tm > mrow + 10.f){               // defer-max; per-lane scalar rescale
        float f = exp2f(mrow - tm);
        mrow = tm;
        lrow *= f;
        #pragma unroll
        for (int dt = 0; dt < 4; ++dt)
          #pragma unroll
          for (int i = 0; i < 16; ++i) acc[dt][i] *= f;
      }
      #pragma unroll
      for (int rr = 0; rr < 16; ++rr) st[rr] = exp2f(st[rr] - mrow);
      #pragma unroll
      for (int p = 0; p < 8; ++p) t8[p] = st[p] + st[p+8];
      #pragma unroll
      for (int p = 0; p < 4; ++p) t8[p] = t8[p] + t8[p+4];
      float rs = (t8[0] + t8[1]) + (t8[2] + t8[3]);
      rs += __shfl_xor(rs, 32);
      lrow += rs;

      unsigned pk[8];
      #pragma unroll
      for (int p = 0; p < 8; ++p){
        unsigned rpk;
        float lo = st[p*2], hi = st[p*2+1];
        asm("v_cvt_pk_bf16_f32 %0, %1, %2" : "=v"(rpk) : "v"(lo), "v"(hi));
        pk[p] = rpk;
      }
      unsigned sA = h ? pk[0] : pk[2], sB = h ? pk[1] : pk[3];
      unsigned sC = h ? pk[4] : pk[6], sD = h ? pk[5] : pk[7];
      unsigned rxA = (unsigned)__shfl_xor((int)sA, 32);
      unsigned rxB = (unsigned)__shfl_xor((int)sB, 32);
      unsigned rxC = (unsigned)__shfl_xor((int)sC, 32);
      unsigned rxD = (unsigned)__shfl_xor((int)sD, 32);
      u32x4 pv0, pv1;
      pv0[0] = h ? rxA : pk[0]; pv0[1] = h ? rxB : pk[1];
      pv0[2] = h ? pk[2] : rxA; pv0[3] = h ? pk[3] : rxB;
      pv1[0] = h ? rxC : pk[4]; pv1[1] = h ? rxD : pk[5];
      pv1[2] = h ? pk[6] : rxC; pv1[3] = h ? pk[7] : rxD;
      s16x8 pa0 = __builtin_bit_cast(s16x8, pv0);
      s16x8 pa1 = __builtin_bit_cast(s16x8, pv1);

      #pragma unroll
      for (int dt = 0; dt < 4; ++dt){
        int vr = dh*128 + dt*32 + l31;
        int swzv = (vr & 7) << 4;
        const char* vbase = Vc + vr*128;
        s16x8 vf0 = *(const s16x8*)(vbase + ((vcol + h*16) ^ swzv));
        acc[dt] = MFMA32(vf0, pa0, acc[dt]);
        s16x8 vf1 = *(const s16x8*)(vbase + ((vcol + 32 + h*16) ^ swzv));
        acc[dt] = MFMA32(vf1, pa1, acc[dt]);
      }
    };
    PROC(st0, (unsigned)mwv64, 0);
    PROC(st1, (unsigned)(mwv64 >> 32), 64);

    __builtin_amdgcn_s_barrier();          // all reads of cur done -> overwrite safe
  }

  // epilogue: per-lane normalize + direct store (lane pair covers full 64B lines)
  float inv = 1.f / lrow;
  unsigned short* hrow = hc + ((size_t)(b*NN + qrow))*(RR*DD) + r*DD;
  #pragma unroll
  for (int dt = 0; dt < 4; ++dt){
    #pragma unroll
    for (int g = 0; g < 4; ++g){
      float a0 = acc[dt][g*4+0]*inv, a1 = acc[dt][g*4+1]*inv;
      float a2 = acc[dt][g*4+2]*inv, a3 = acc[dt][g*4+3]*inv;
      unsigned r0, r1;
      asm("v_cvt_pk_bf16_f32 %0, %1, %2" : "=v"(r0) : "v"(a0), "v"(a1));
      asm("v_cvt_pk_bf16_f32 %0, %1, %2" : "=v"(r1) : "v"(a2), "v"(a3));
      int d = dh*128 + dt*32 + 8*g + 4*h;
      u32x2 pv; pv[0] = r0; pv[1] = r1;
      *(u32x2*)(hrow + d) = pv;
    }
  }
}

// ------------- FF GEMM: A=hc (K=512), out f32 (stride 256) -------------
__global__ __launch_bounds__(256) void gemm_ff(const unsigned short* __restrict__ A,
    const unsigned short* __restrict__ Wt, const float* __restrict__ bias,
    float* __restrict__ out){
  __shared__ unsigned short As[2][128*32];
  __shared__ unsigned short Bs[2][128*32];
  int t = threadIdx.x, lane = t & 63, w = t >> 6;
  int wr = w >> 1, wc = w & 1, l15 = lane & 15, lhi = lane >> 4;
  int bm = blockIdx.x, bn = blockIdx.y;
  f32x4 acc[4][4];
  #pragma unroll
  for (int m = 0; m < 4; ++m)
    #pragma unroll
    for (int n = 0; n < 4; ++n) acc[m][n] = (f32x4){0.f,0.f,0.f,0.f};

  auto STAGE = [&](int bi, int kk){
    #pragma unroll
    for (int i = 0; i < 2; ++i){
      int base = w*2048 + i*1024;
      int off = base + lane*16;
      int row = off >> 6, cb = off & 63;
      gload16((const char*)A  + ((size_t)(bm*128 + row)*512 + kk*32)*2 + cb,
              (char*)As[bi] + base);
      gload16((const char*)Wt + ((size_t)(bn*128 + row)*512 + kk*32)*2 + cb,
              (char*)Bs[bi] + base);
    }
  };

  STAGE(0, 0);
  __syncthreads();
  for (int kk = 0; kk < 16; ++kk){
    int cur = kk & 1;
    if (kk + 1 < 16) STAGE(cur ^ 1, kk + 1);
    s16x8 af[4], bfr[4];
    #pragma unroll
    for (int m = 0; m < 4; ++m) af[m]  = *(const s16x8*)&As[cur][(wr*64 + m*16 + l15)*32 + lhi*8];
    #pragma unroll
    for (int n = 0; n < 4; ++n) bfr[n] = *(const s16x8*)&Bs[cur][(wc*64 + n*16 + l15)*32 + lhi*8];
    __builtin_amdgcn_s_setprio(1);
    #pragma unroll
    for (int m = 0; m < 4; ++m)
      #pragma unroll
      for (int n = 0; n < 4; ++n)
        acc[m][n] = MFMA16(af[m], bfr[n], acc[m][n]);
    __builtin_amdgcn_s_setprio(0);
    __syncthreads();
  }

  #pragma unroll
  for (int n = 0; n < 4; ++n){
    int gn = bn*128 + wc*64 + n*16 + l15;
    float bv = bias[gn];
    #pragma unroll
    for (int m = 0; m < 4; ++m){
      int gm = bm*128 + wr*64 + m*16 + lhi*4;
      #pragma unroll
      for (int i = 0; i < 4; ++i)
        out[(size_t)(gm + i)*DD + gn] = acc[m][n][i] + bv;
    }
  }
}

// ------------- relu + residual + layernorm (+ optional hbf write) -------------
template<int WRITEH>
__global__ __launch_bounds__(256) void ln_res2(const float* __restrict__ ff,
    const float* __restrict__ hin, const float* __restrict__ g,
    const float* __restrict__ bv, float* __restrict__ hout,
    unsigned short* __restrict__ hbf){
  int w = threadIdx.x >> 6, lane = threadIdx.x & 63;
  size_t row = (size_t)blockIdx.x * 4 + w;
  f32x4 fv = *(const f32x4*)(ff  + row*DD + lane*4);
  f32x4 hv = *(const f32x4*)(hin + row*DD + lane*4);
  float x[4], s = 0.f, ss = 0.f;
  #pragma unroll
  for (int j = 0; j < 4; ++j){ x[j] = fmaxf(fv[j], 0.f) + hv[j]; s += x[j]; ss += x[j]*x[j]; }
  #pragma unroll
  for (int xm = 1; xm < 64; xm <<= 1){ s += __shfl_xor(s, xm); ss += __shfl_xor(ss, xm); }
  float mu = s * (1.f/256.f);
  float var = ss * (1.f/256.f) - mu*mu;
  float rstd = rsqrtf(var + 1e-5f);
  f32x4 o;
  #pragma unroll
  for (int j = 0; j < 4; ++j){ int c = lane*4 + j; o[j] = (x[j]-mu)*rstd*g[c] + bv[c]; }
  *(f32x4*)(hout + row*DD + lane*4) = o;
  if (WRITEH){
    uint2 pv;
    pv.x = (unsigned)f2bf(o[0]) | ((unsigned)f2bf(o[1]) << 16);
    pv.y = (unsigned)f2bf(o[2]) | ((unsigned)f2bf(o[3]) << 16);
    *(uint2*)(hbf + row*DD + lane*4) = pv;
  }
}

extern "C" void kernel_launch(void* const* d_in, const int* in_sizes, int n_in,
                              void* d_out, int out_size, void* d_ws, size_t ws_size,
                              hipStream_t stream){
  (void)in_sizes; (void)n_in; (void)out_size; (void)ws_size;
  const float* node  = (const float*)d_in[0];
  const float* inx   = (const float*)d_in[1];
  const int*   adj   = (const int*)d_in[2];
  const float* WQi_w = (const float*)d_in[3];
  const float* WQi_b = (const float*)d_in[4];
  const float* WQ_w  = (const float*)d_in[5];
  const float* WQ_b  = (const float*)d_in[6];
  const float* WK_w  = (const float*)d_in[7];
  const float* WK_b  = (const float*)d_in[8];
  const float* WV_w  = (const float*)d_in[9];
  const float* WV_b  = (const float*)d_in[10];
  const float* WF_w  = (const float*)d_in[11];
  const float* WF_b  = (const float*)d_in[12];
  const float* ln_g  = (const float*)d_in[13];
  const float* ln_b  = (const float*)d_in[14];
  float* hout = (float*)d_out;

  char* wsp = (char*)d_ws;
  auto alloc = [&](size_t n){ char* p = wsp; wsp += (n + 255) & ~(size_t)255; return p; };
  unsigned long long* bits = (unsigned long long*)alloc((size_t)RR*BB*NN*16*8);
  unsigned short* wtall = (unsigned short*)alloc((size_t)2*NPROJ*DF*2);
  unsigned short* wtf   = (unsigned short*)alloc((size_t)2*DD*512*2);
  float*          ball  = (float*)alloc((size_t)2*NPROJ*4);
  unsigned short* x1bf  = (unsigned short*)alloc((size_t)2*BB*FF_*2);
  unsigned short* hbf   = (unsigned short*)alloc((size_t)MM*DD*2);
  unsigned short* POUT  = (unsigned short*)alloc((size_t)MM*PK*2);
  unsigned short* vtall = (unsigned short*)alloc((size_t)RR*BB*DD*NN*2);
  unsigned short* hc    = (unsigned short*)alloc((size_t)MM*512*2);
  float*          ffo   = (float*)alloc((size_t)MM*DD*4);

  pack_adj<<<RR*BB*NN/4, 256, 0, stream>>>(adj, bits);
  prep<<<PREP_TOT, 256, 0, stream>>>(node, inx, WQi_w, WQi_b, WQ_w, WK_w, WV_w,
                                     WQ_b, WK_b, WV_b, WF_w,
                                     wtall, wtf, ball, x1bf, hbf);

  for (int l = 0; l < LL; ++l){
    gemm_big<<<dim3(128,10), 256, 0, stream>>>(hbf, x1bf + (size_t)l*BB*FF_,
        wtall + (size_t)l*NPROJ*DF, ball + (size_t)l*NPROJ, POUT, vtall);

    attn10<<<256, 512, 0, stream>>>(POUT, vtall, bits, hc);

    gemm_ff<<<dim3(128,2), 256, 0, stream>>>(hc, wtf + (size_t)l*DD*512, WF_b + l*DD, ffo);

    if (l == 0) ln_res2<1><<<MM/4, 256, 0, stream>>>(ffo, node, ln_g, ln_b, hout, hbf);
    else        ln_res2<0><<<MM/4, 256, 0, stream>>>(ffo, (const float*)hout,
                                                     ln_g + DD, ln_b + DD, hout, nullptr);
  }
}

// Round 13
// 297.725 us; speedup vs baseline: 1.0202x; 1.0202x over previous
//
#include <hip/hip_runtime.h>
#include <hip/hip_bf16.h>

#define BB 16
#define NN 1024
#define DD 256
#define FF_ 128
#define LL 2
#define RR 2
#define DF 384
#define MM (BB*NN)
#define NPROJ 1280
#define PK 768            // POUT row stride (Q:0..255, K0:256..511, K1:512..767)
#define CSC 0.09016844f   // (1/16) * log2(e), folded into WQ at prep

typedef __attribute__((ext_vector_type(8))) short s16x8;
typedef __attribute__((ext_vector_type(4))) float f32x4;
typedef __attribute__((ext_vector_type(16))) float f32x16;
typedef __attribute__((ext_vector_type(2))) unsigned int u32x2;
typedef __attribute__((ext_vector_type(4))) unsigned int u32x4;
typedef __attribute__((ext_vector_type(4))) unsigned short us16x4;

__device__ __forceinline__ unsigned short f2bf(float f){
  unsigned u = __builtin_bit_cast(unsigned, f);
  u += 0x7fff + ((u >> 16) & 1);
  return (unsigned short)(u >> 16);
}

__device__ __forceinline__ void gload16(const void* g, void* l){
  __builtin_amdgcn_global_load_lds(
      (const __attribute__((address_space(1))) unsigned int*)g,
      (__attribute__((address_space(3))) unsigned int*)l, 16, 0, 0);
}

#define MFMA16(a,b,c) __builtin_amdgcn_mfma_f32_16x16x32_bf16((a),(b),(c),0,0,0)
#define MFMA32(a,b,c) __builtin_amdgcn_mfma_f32_32x32x16_bf16((a),(b),(c),0,0,0)

// ---------------- one-shot prep: weights, biases, x1, hbf, adj bitmasks ----------------
#define PREP_WT   3840
#define PREP_WTF  1024
#define PREP_BALL 10
#define PREP_X1   16
#define PREP_H    2048
#define PREP_TOT  (PREP_WT+PREP_WTF+PREP_BALL+PREP_X1+PREP_H)
#define PREP_ADJ  8192
#define PREP_ALL  (PREP_TOT+PREP_ADJ)

__global__ __launch_bounds__(256) void prep(
    const float* __restrict__ node, const float* __restrict__ inx,
    const float* __restrict__ WQi_w, const float* __restrict__ WQi_b,
    const float* __restrict__ WQ_w, const float* __restrict__ WK_w,
    const float* __restrict__ WV_w, const float* __restrict__ WQ_b,
    const float* __restrict__ WK_b, const float* __restrict__ WV_b,
    const float* __restrict__ WF_w, const int* __restrict__ adj,
    unsigned short* __restrict__ wtall, unsigned short* __restrict__ wtf,
    float* __restrict__ ball, unsigned short* __restrict__ x1bf,
    unsigned short* __restrict__ hbf, unsigned long long* __restrict__ bits){
  int bid = blockIdx.x, t = threadIdx.x;
  if (bid < PREP_WT){
    int o = bid*256 + t;                       // < 2*1280*384
    int l = o / (NPROJ*DF); int oo = o - l*(NPROJ*DF);
    int n = oo / DF, k = oo - n*DF;
    const float* WQ = WQ_w + (size_t)l*DF*256;
    const float* WK = WK_w + (size_t)l*RR*DF*256;
    const float* WV = WV_w + (size_t)l*RR*DF*256;
    float v;
    if (n < 256)      v = WQ[(size_t)k*256 + n] * CSC;   // fold attn scale into Q
    else if (n < 768) v = WK[(size_t)((n-256)>>8)*(DF*256) + (size_t)k*256 + ((n-256)&255)];
    else              v = WV[(size_t)((n-768)>>8)*(DF*256) + (size_t)k*256 + ((n-768)&255)];
    wtall[o] = f2bf(v);
  } else if (bid < PREP_WT + PREP_WTF){
    int o = (bid - PREP_WT)*256 + t;           // < 2*512*256
    int l = o >> 17; int oo = o & 131071;
    int n = oo >> 9, k = oo & 511;
    wtf[o] = f2bf(WF_w[(size_t)l*512*256 + (size_t)k*256 + n]);
  } else if (bid < PREP_WT + PREP_WTF + PREP_BALL){
    int o = (bid - PREP_WT - PREP_WTF)*256 + t;
    if (o < 2*NPROJ){
      int l = o / NPROJ, n = o - l*NPROJ;
      float v = (n < 256) ? WQ_b[l*256 + n] * CSC
              : (n < 768) ? WK_b[(size_t)l*512 + (n-256)]
                          : WV_b[(size_t)l*512 + (n-768)];
      ball[o] = v;
    }
  } else if (bid < PREP_WT + PREP_WTF + PREP_BALL + PREP_X1){
    int o = (bid - PREP_WT - PREP_WTF - PREP_BALL)*256 + t;  // < 4096
    int l = o >> 11, bj = o & 2047;
    int b = bj >> 7, j = bj & 127;
    const float* w = WQi_w + (size_t)l*FF_*FF_;
    float s = WQi_b[l*FF_ + j];
    for (int i = 0; i < FF_; ++i) s += inx[b*FF_ + i] * w[i*FF_ + j];
    x1bf[o] = f2bf(s);
  } else if (bid < PREP_TOT){
    int o = (bid - (PREP_TOT - PREP_H))*256 + t;             // < 524288, 8 elems each
    const float4* src = (const float4*)node + (size_t)o*2;
    float4 a = src[0], c = src[1];
    uint4 pk;
    pk.x = (unsigned)f2bf(a.x) | ((unsigned)f2bf(a.y) << 16);
    pk.y = (unsigned)f2bf(a.z) | ((unsigned)f2bf(a.w) << 16);
    pk.z = (unsigned)f2bf(c.x) | ((unsigned)f2bf(c.y) << 16);
    pk.w = (unsigned)f2bf(c.z) | ((unsigned)f2bf(c.w) << 16);
    *(uint4*)(hbf + (size_t)o*8) = pk;
  } else {
    // adj -> bitmask (R,B,N, 16 x u64)
    int w = t >> 6, lane = t & 63;
    size_t row = (size_t)(bid - PREP_TOT) * 4 + w;
    const int* a = adj + row * NN;
    unsigned long long* brow = bits + row * 16;
    #pragma unroll
    for (int j = 0; j < 16; ++j){
      unsigned long long m = __ballot(a[j*64 + lane] != 0);
      if (lane == 0) brow[j] = m;
    }
  }
}

// ------------- big projection GEMM: A=concat(hbf,x1), N=1280, K=384 -------------
// counted-vmcnt split-barrier loop (T4). bn<6: POUT. bn>=6: V transposed to vtall.
__global__ __launch_bounds__(256) void gemm_big(const unsigned short* __restrict__ hbf,
    const unsigned short* __restrict__ x1l, const unsigned short* __restrict__ Wt,
    const float* __restrict__ bias, unsigned short* __restrict__ POUT,
    unsigned short* __restrict__ vtall){
  __shared__ unsigned short As[2][128*32];
  __shared__ unsigned short Bs[2][128*32];
  int t = threadIdx.x, lane = t & 63, w = t >> 6;
  int wr = w >> 1, wc = w & 1, l15 = lane & 15, lhi = lane >> 4;
  int bm = blockIdx.x, bn = blockIdx.y, bb = bm >> 3;
  f32x4 acc[4][4];
  #pragma unroll
  for (int m = 0; m < 4; ++m)
    #pragma unroll
    for (int n = 0; n < 4; ++n) acc[m][n] = (f32x4){0.f,0.f,0.f,0.f};

  auto STAGE = [&](int bi, int kk){
    #pragma unroll
    for (int i = 0; i < 2; ++i){
      int base = w*2048 + i*1024;
      int off = base + lane*16;
      int row = off >> 6, cb = off & 63;
      const char* asrc = (kk < 8)
        ? (const char*)hbf + ((size_t)(bm*128 + row)*256 + kk*32)*2 + cb
        : (const char*)x1l + ((size_t)bb*128 + (kk-8)*32)*2 + cb;
      gload16(asrc, (char*)As[bi] + base);
      gload16((const char*)Wt + ((size_t)(bn*128 + row)*DF + kk*32)*2 + cb,
              (char*)Bs[bi] + base);
    }
  };

  STAGE(0, 0);
  for (int kk = 0; kk < 12; ++kk){
    int cur = kk & 1;
    if (kk + 1 < 12){
      STAGE(cur ^ 1, kk + 1);
      asm volatile("s_waitcnt vmcnt(4)" ::: "memory");
    } else {
      asm volatile("s_waitcnt vmcnt(0)" ::: "memory");
    }
    __builtin_amdgcn_s_barrier();
    __builtin_amdgcn_sched_barrier(0);
    s16x8 af[4], bfr[4];
    #pragma unroll
    for (int m = 0; m < 4; ++m) af[m]  = *(const s16x8*)&As[cur][(wr*64 + m*16 + l15)*32 + lhi*8];
    #pragma unroll
    for (int n = 0; n < 4; ++n) bfr[n] = *(const s16x8*)&Bs[cur][(wc*64 + n*16 + l15)*32 + lhi*8];
    __builtin_amdgcn_s_setprio(1);
    #pragma unroll
    for (int m = 0; m < 4; ++m)
      #pragma unroll
      for (int n = 0; n < 4; ++n)
        acc[m][n] = MFMA16(af[m], bfr[n], acc[m][n]);
    __builtin_amdgcn_s_setprio(0);
    __builtin_amdgcn_s_barrier();            // all reads of cur done -> overwrite safe
  }

  if (bn < 6){
    #pragma unroll
    for (int n = 0; n < 4; ++n){
      int gn = bn*128 + wc*64 + n*16 + l15;
      float bv = bias[gn];
      #pragma unroll
      for (int m = 0; m < 4; ++m){
        int gm = bm*128 + wr*64 + m*16 + lhi*4;
        #pragma unroll
        for (int i = 0; i < 4; ++i)
          POUT[(size_t)(gm + i)*PK + gn] = f2bf(acc[m][n][i] + bv);
      }
    }
  } else {
    #pragma unroll
    for (int n = 0; n < 4; ++n){
      int gn = bn*128 + wc*64 + n*16 + l15;
      float bv = bias[gn];
      int rv = gn - 768;
      int r = rv >> 8, d = rv & 255;
      #pragma unroll
      for (int m = 0; m < 4; ++m){
        int mb = (bm & 7)*128 + wr*64 + m*16 + lhi*4;
        us16x4 pk;
        #pragma unroll
        for (int i = 0; i < 4; ++i) pk[i] = f2bf(acc[m][n][i] + bv);
        *(us16x4*)(vtall + ((size_t)((r*16 + bb)*256 + d))*NN + mb) = pk;
      }
    }
  }
}

// ------------- flash attention v11: attn10 + MFMA row-sum + merged max + setprio ----
// grid 256 (XCD-swizzled), block 512 = 4 qsubs x 2 d-halves, dbuf counted vmcnt.
__global__ __launch_bounds__(512, 1) void attn11(const unsigned short* __restrict__ P,
    const unsigned short* __restrict__ VT, const unsigned long long* __restrict__ bits,
    unsigned short* __restrict__ hc){
  __shared__ char smem[147456];

  int t = threadIdx.x, lane = t & 63, w = t >> 6;
  int h = lane >> 5, l31 = lane & 31;
  int qsub = w >> 1, dh = w & 1;          // q-subtile, d-half
  int F = blockIdx.x;
  int xcd = F & 7, j = F >> 3;
  int qt = j & 7;
  int gidx = xcd*4 + (j >> 3);
  int b = gidx & 15, r = gidx >> 4;

  size_t kcol = 256 + (size_t)r*256;
  const unsigned short* Vb = VT + ((size_t)(r*16 + b))*256*NN;
  int qrow = qt*128 + qsub*32 + l31;

  // Q in registers: 16 B-operand frags (lane = q-col, full D), pre-scaled by CSC
  s16x8 qf[16];
  {
    const unsigned short* qp = P + ((size_t)(b*NN + qrow))*PK + h*8;
    #pragma unroll
    for (int d_ = 0; d_ < 16; ++d_) qf[d_] = *(const s16x8*)(qp + d_*16);
  }

  // stage all masks for this block's 128 q-rows into LDS [kt][row]
  {
    const unsigned long long* bb0 = bits + ((size_t)(r*BB + b)*NN + qt*128)*16;
    unsigned long long* ml = (unsigned long long*)(smem + 131072);
    #pragma unroll
    for (int i = 0; i < 4; ++i){
      int idx = t + i*512;                // < 2048
      int kt = idx >> 7, row = idx & 127;
      ml[kt*128 + row] = bb0[(size_t)row*16 + kt];
    }
  }

  s16x8 ones;
  #pragma unroll
  for (int i = 0; i < 8; ++i) ones[i] = (short)0x3F80;   // bf16 1.0

  f32x16 acc[4];                           // d-half: d in [dh*128, dh*128+128)
  #pragma unroll
  for (int dt = 0; dt < 4; ++dt)
    #pragma unroll
    for (int i = 0; i < 16; ++i) acc[dt][i] = 0.f;
  f32x16 accl;                             // row-sum accumulator (only [0] read)
  #pragma unroll
  for (int i = 0; i < 16; ++i) accl[i] = 0.f;
  float mrow = -3e38f;

  auto STAGE = [&](int buf, int kt){
    char* base = smem + buf*65536;
    #pragma unroll
    for (int i = 0; i < 4; ++i){
      int o = i*8192 + t*16;              // [0,32768)
      int kr = o >> 9, cb = o & 511;
      int lcb = cb ^ ((kr & 7) << 4);
      gload16((const char*)P + ((size_t)(b*NN + kt*64 + kr)*PK + kcol)*2 + lcb,
              base + o);
    }
    #pragma unroll
    for (int i = 0; i < 4; ++i){
      int o = i*8192 + t*16;
      int vr = o >> 7, cb = o & 127;
      int lcb = cb ^ ((vr & 7) << 4);
      gload16((const char*)Vb + ((size_t)vr*NN + kt*64)*2 + lcb,
              base + 32768 + o);
    }
  };

  STAGE(0, 0);
  __syncthreads();                         // drains Q/mask reads + ds_writes + stage0

  for (int kt = 0; kt < 16; ++kt){
    int cur = kt & 1;
    if (kt + 1 < 16){
      STAGE(cur ^ 1, kt + 1);
      asm volatile("s_waitcnt vmcnt(8)" ::: "memory");
    } else {
      asm volatile("s_waitcnt vmcnt(0)" ::: "memory");
    }
    __builtin_amdgcn_s_barrier();          // cur tiles ready in all waves
    __builtin_amdgcn_sched_barrier(0);

    unsigned long long mwv64 = *(const unsigned long long*)
        (smem + 131072 + kt*1024 + (qsub*32 + l31)*8);

    const char* Kc = smem + cur*65536;
    const char* Vc = smem + cur*65536 + 32768;

    // QK: dual independent chains over both 32-k subtiles, D=256
    f32x16 st0, st1;
    #pragma unroll
    for (int i = 0; i < 16; ++i){ st0[i] = 0.f; st1[i] = 0.f; }
    int swzk = (l31 & 7) << 4;
    const char* kb0 = Kc + l31*512;
    const char* kb1 = Kc + (32 + l31)*512;
    __builtin_amdgcn_s_setprio(1);
    #pragma unroll
    for (int d_ = 0; d_ < 16; ++d_){
      int co = (d_*32 + h*16) ^ swzk;
      s16x8 kf0 = *(const s16x8*)(kb0 + co);
      s16x8 kf1 = *(const s16x8*)(kb1 + co);
      st0 = MFMA32(kf0, qf[d_], st0);
      st1 = MFMA32(kf1, qf[d_], st1);
    }
    __builtin_amdgcn_s_setprio(0);

    // mask both subtiles (h folded into mask shift; bit index compile-time)
    unsigned mw0 = (unsigned)mwv64 >> (h*4);
    unsigned mw1 = (unsigned)(mwv64 >> 32) >> (h*4);
    #pragma unroll
    for (int rr = 0; rr < 16; ++rr){
      const int kb = (rr & 3) + 8*(rr >> 2);
      st0[rr] = ((mw0 >> kb) & 1u) ? st0[rr] : -1.443e9f;
      st1[rr] = ((mw1 >> kb) & 1u) ? st1[rr] : -1.443e9f;
    }
    // merged max over both subtiles, single shfl, single defer-max decision
    float t8[8];
    #pragma unroll
    for (int p = 0; p < 8; ++p) t8[p] = fmaxf(fmaxf(st0[p], st0[p+8]),
                                              fmaxf(st1[p], st1[p+8]));
    #pragma unroll
    for (int p = 0; p < 4; ++p) t8[p] = fmaxf(t8[p], t8[p+4]);
    float tm = fmaxf(fmaxf(t8[0], t8[1]), fmaxf(t8[2], t8[3]));
    tm = fmaxf(tm, __shfl_xor(tm, 32));
    if (tm > mrow + 10.f){                 // defer-max; per-lane scalar rescale
      float f = exp2f(mrow - tm);
      mrow = tm;
      accl[0] *= f;
      #pragma unroll
      for (int dt = 0; dt < 4; ++dt)
        #pragma unroll
        for (int i = 0; i < 16; ++i) acc[dt][i] *= f;
    }
    #pragma unroll
    for (int rr = 0; rr < 16; ++rr){
      st0[rr] = exp2f(st0[rr] - mrow);
      st1[rr] = exp2f(st1[rr] - mrow);
    }

    // pack P -> bf16 pairs (cvt_pk), half-wave exchange -> 4 A-frags
    unsigned pk0[8], pk1[8];
    #pragma unroll
    for (int p = 0; p < 8; ++p){
      unsigned r0, r1;
      float a0 = st0[p*2], a1 = st0[p*2+1];
      float b0 = st1[p*2], b1 = st1[p*2+1];
      asm("v_cvt_pk_bf16_f32 %0, %1, %2" : "=v"(r0) : "v"(a0), "v"(a1));
      asm("v_cvt_pk_bf16_f32 %0, %1, %2" : "=v"(r1) : "v"(b0), "v"(b1));
      pk0[p] = r0; pk1[p] = r1;
    }
    s16x8 pa00, pa01, pa10, pa11;
    {
      unsigned sA = h ? pk0[0] : pk0[2], sB = h ? pk0[1] : pk0[3];
      unsigned sC = h ? pk0[4] : pk0[6], sD = h ? pk0[5] : pk0[7];
      unsigned rxA = (unsigned)__shfl_xor((int)sA, 32);
      unsigned rxB = (unsigned)__shfl_xor((int)sB, 32);
      unsigned rxC = (unsigned)__shfl_xor((int)sC, 32);
      unsigned rxD = (unsigned)__shfl_xor((int)sD, 32);
      u32x4 v0, v1;
      v0[0] = h ? rxA : pk0[0]; v0[1] = h ? rxB : pk0[1];
      v0[2] = h ? pk0[2] : rxA; v0[3] = h ? pk0[3] : rxB;
      v1[0] = h ? rxC : pk0[4]; v1[1] = h ? rxD : pk0[5];
      v1[2] = h ? pk0[6] : rxC; v1[3] = h ? pk0[7] : rxD;
      pa00 = __builtin_bit_cast(s16x8, v0);
      pa01 = __builtin_bit_cast(s16x8, v1);
    }
    {
      unsigned sA = h ? pk1[0] : pk1[2], sB = h ? pk1[1] : pk1[3];
      unsigned sC = h ? pk1[4] : pk1[6], sD = h ? pk1[5] : pk1[7];
      unsigned rxA = (unsigned)__shfl_xor((int)sA, 32);
      unsigned rxB = (unsigned)__shfl_xor((int)sB, 32);
      unsigned rxC = (unsigned)__shfl_xor((int)sC, 32);
      unsigned rxD = (unsigned)__shfl_xor((int)sD, 32);
      u32x4 v0, v1;
      v0[0] = h ? rxA : pk1[0]; v0[1] = h ? rxB : pk1[1];
      v0[2] = h ? pk1[2] : rxA; v0[3] = h ? pk1[3] : rxB;
      v1[0] = h ? rxC : pk1[4]; v1[1] = h ? rxD : pk1[5];
      v1[2] = h ? pk1[6] : rxC; v1[3] = h ? pk1[7] : rxD;
      pa10 = __builtin_bit_cast(s16x8, v0);
      pa11 = __builtin_bit_cast(s16x8, v1);
    }

    // PV + MFMA row-sum (ones trick replaces VALU sum-tree + shfl)
    __builtin_amdgcn_s_setprio(1);
    accl = MFMA32(ones, pa00, accl);
    accl = MFMA32(ones, pa01, accl);
    accl = MFMA32(ones, pa10, accl);
    accl = MFMA32(ones, pa11, accl);
    #pragma unroll
    for (int dt = 0; dt < 4; ++dt){
      int vr = dh*128 + dt*32 + l31;
      int swzv = (vr & 7) << 4;
      const char* vbase = Vc + vr*128;
      s16x8 vf0 = *(const s16x8*)(vbase + ((h*16) ^ swzv));
      acc[dt] = MFMA32(vf0, pa00, acc[dt]);
      s16x8 vf1 = *(const s16x8*)(vbase + ((32 + h*16) ^ swzv));
      acc[dt] = MFMA32(vf1, pa01, acc[dt]);
      s16x8 vf2 = *(const s16x8*)(vbase + ((64 + h*16) ^ swzv));
      acc[dt] = MFMA32(vf2, pa10, acc[dt]);
      s16x8 vf3 = *(const s16x8*)(vbase + ((96 + h*16) ^ swzv));
      acc[dt] = MFMA32(vf3, pa11, acc[dt]);
    }
    __builtin_amdgcn_s_setprio(0);

    __builtin_amdgcn_s_barrier();          // all reads of cur done -> overwrite safe
  }

  // epilogue: per-lane normalize + direct store
  float inv = 1.f / accl[0];
  unsigned short* hrow = hc + ((size_t)(b*NN + qrow))*(RR*DD) + r*DD;
  #pragma unroll
  for (int dt = 0; dt < 4; ++dt){
    #pragma unroll
    for (int g = 0; g < 4; ++g){
      float a0 = acc[dt][g*4+0]*inv, a1 = acc[dt][g*4+1]*inv;
      float a2 = acc[dt][g*4+2]*inv, a3 = acc[dt][g*4+3]*inv;
      unsigned r0, r1;
      asm("v_cvt_pk_bf16_f32 %0, %1, %2" : "=v"(r0) : "v"(a0), "v"(a1));
      asm("v_cvt_pk_bf16_f32 %0, %1, %2" : "=v"(r1) : "v"(a2), "v"(a3));
      int d = dh*128 + dt*32 + 8*g + 4*h;
      u32x2 pv; pv[0] = r0; pv[1] = r1;
      *(u32x2*)(hrow + d) = pv;
    }
  }
}

// ------------- FF GEMM: A=hc (K=512), out f32, counted-vmcnt loop -------------
__global__ __launch_bounds__(256) void gemm_ff(const unsigned short* __restrict__ A,
    const unsigned short* __restrict__ Wt, const float* __restrict__ bias,
    float* __restrict__ out){
  __shared__ unsigned short As[2][128*32];
  __shared__ unsigned short Bs[2][128*32];
  int t = threadIdx.x, lane = t & 63, w = t >> 6;
  int wr = w >> 1, wc = w & 1, l15 = lane & 15, lhi = lane >> 4;
  int bm = blockIdx.x, bn = blockIdx.y;
  f32x4 acc[4][4];
  #pragma unroll
  for (int m = 0; m < 4; ++m)
    #pragma unroll
    for (int n = 0; n < 4; ++n) acc[m][n] = (f32x4){0.f,0.f,0.f,0.f};

  auto STAGE = [&](int bi, int kk){
    #pragma unroll
    for (int i = 0; i < 2; ++i){
      int base = w*2048 + i*1024;
      int off = base + lane*16;
      int row = off >> 6, cb = off & 63;
      gload16((const char*)A  + ((size_t)(bm*128 + row)*512 + kk*32)*2 + cb,
              (char*)As[bi] + base);
      gload16((const char*)Wt + ((size_t)(bn*128 + row)*512 + kk*32)*2 + cb,
              (char*)Bs[bi] + base);
    }
  };

  STAGE(0, 0);
  for (int kk = 0; kk < 16; ++kk){
    int cur = kk & 1;
    if (kk + 1 < 16){
      STAGE(cur ^ 1, kk + 1);
      asm volatile("s_waitcnt vmcnt(4)" ::: "memory");
    } else {
      asm volatile("s_waitcnt vmcnt(0)" ::: "memory");
    }
    __builtin_amdgcn_s_barrier();
    __builtin_amdgcn_sched_barrier(0);
    s16x8 af[4], bfr[4];
    #pragma unroll
    for (int m = 0; m < 4; ++m) af[m]  = *(const s16x8*)&As[cur][(wr*64 + m*16 + l15)*32 + lhi*8];
    #pragma unroll
    for (int n = 0; n < 4; ++n) bfr[n] = *(const s16x8*)&Bs[cur][(wc*64 + n*16 + l15)*32 + lhi*8];
    __builtin_amdgcn_s_setprio(1);
    #pragma unroll
    for (int m = 0; m < 4; ++m)
      #pragma unroll
      for (int n = 0; n < 4; ++n)
        acc[m][n] = MFMA16(af[m], bfr[n], acc[m][n]);
    __builtin_amdgcn_s_setprio(0);
    __builtin_amdgcn_s_barrier();
  }

  #pragma unroll
  for (int n = 0; n < 4; ++n){
    int gn = bn*128 + wc*64 + n*16 + l15;
    float bv = bias[gn];
    #pragma unroll
    for (int m = 0; m < 4; ++m){
      int gm = bm*128 + wr*64 + m*16 + lhi*4;
      #pragma unroll
      for (int i = 0; i < 4; ++i)
        out[(size_t)(gm + i)*DD + gn] = acc[m][n][i] + bv;
    }
  }
}

// ------------- relu + residual + layernorm (+ optional hbf write) -------------
template<int WRITEH>
__global__ __launch_bounds__(256) void ln_res2(const float* __restrict__ ff,
    const float* __restrict__ hin, const float* __restrict__ g,
    const float* __restrict__ bv, float* __restrict__ hout,
    unsigned short* __restrict__ hbf){
  int w = threadIdx.x >> 6, lane = threadIdx.x & 63;
  size_t row = (size_t)blockIdx.x * 4 + w;
  f32x4 fv = *(const f32x4*)(ff  + row*DD + lane*4);
  f32x4 hv = *(const f32x4*)(hin + row*DD + lane*4);
  float x[4], s = 0.f, ss = 0.f;
  #pragma unroll
  for (int j = 0; j < 4; ++j){ x[j] = fmaxf(fv[j], 0.f) + hv[j]; s += x[j]; ss += x[j]*x[j]; }
  #pragma unroll
  for (int xm = 1; xm < 64; xm <<= 1){ s += __shfl_xor(s, xm); ss += __shfl_xor(ss, xm); }
  float mu = s * (1.f/256.f);
  float var = ss * (1.f/256.f) - mu*mu;
  float rstd = rsqrtf(var + 1e-5f);
  f32x4 o;
  #pragma unroll
  for (int j = 0; j < 4; ++j){ int c = lane*4 + j; o[j] = (x[j]-mu)*rstd*g[c] + bv[c]; }
  *(f32x4*)(hout + row*DD + lane*4) = o;
  if (WRITEH){
    uint2 pv;
    pv.x = (unsigned)f2bf(o[0]) | ((unsigned)f2bf(o[1]) << 16);
    pv.y = (unsigned)f2bf(o[2]) | ((unsigned)f2bf(o[3]) << 16);
    *(uint2*)(hbf + row*DD + lane*4) = pv;
  }
}

extern "C" void kernel_launch(void* const* d_in, const int* in_sizes, int n_in,
                              void* d_out, int out_size, void* d_ws, size_t ws_size,
                              hipStream_t stream){
  (void)in_sizes; (void)n_in; (void)out_size; (void)ws_size;
  const float* node  = (const float*)d_in[0];
  const float* inx   = (const float*)d_in[1];
  const int*   adj   = (const int*)d_in[2];
  const float* WQi_w = (const float*)d_in[3];
  const float* WQi_b = (const float*)d_in[4];
  const float* WQ_w  = (const float*)d_in[5];
  const float* WQ_b  = (const float*)d_in[6];
  const float* WK_w  = (const float*)d_in[7];
  const float* WK_b  = (const float*)d_in[8];
  const float* WV_w  = (const float*)d_in[9];
  const float* WV_b  = (const float*)d_in[10];
  const float* WF_w  = (const float*)d_in[11];
  const float* WF_b  = (const float*)d_in[12];
  const float* ln_g  = (const float*)d_in[13];
  const float* ln_b  = (const float*)d_in[14];
  float* hout = (float*)d_out;

  char* wsp = (char*)d_ws;
  auto alloc = [&](size_t n){ char* p = wsp; wsp += (n + 255) & ~(size_t)255; return p; };
  unsigned long long* bits = (unsigned long long*)alloc((size_t)RR*BB*NN*16*8);
  unsigned short* wtall = (unsigned short*)alloc((size_t)2*NPROJ*DF*2);
  unsigned short* wtf   = (unsigned short*)alloc((size_t)2*DD*512*2);
  float*          ball  = (float*)alloc((size_t)2*NPROJ*4);
  unsigned short* x1bf  = (unsigned short*)alloc((size_t)2*BB*FF_*2);
  unsigned short* hbf   = (unsigned short*)alloc((size_t)MM*DD*2);
  unsigned short* POUT  = (unsigned short*)alloc((size_t)MM*PK*2);
  unsigned short* vtall = (unsigned short*)alloc((size_t)RR*BB*DD*NN*2);
  unsigned short* hc    = (unsigned short*)alloc((size_t)MM*512*2);
  float*          ffo   = (float*)alloc((size_t)MM*DD*4);

  prep<<<PREP_ALL, 256, 0, stream>>>(node, inx, WQi_w, WQi_b, WQ_w, WK_w, WV_w,
                                     WQ_b, WK_b, WV_b, WF_w, adj,
                                     wtall, wtf, ball, x1bf, hbf, bits);

  for (int l = 0; l < LL; ++l){
    gemm_big<<<dim3(128,10), 256, 0, stream>>>(hbf, x1bf + (size_t)l*BB*FF_,
        wtall + (size_t)l*NPROJ*DF, ball + (size_t)l*NPROJ, POUT, vtall);

    attn11<<<256, 512, 0, stream>>>(POUT, vtall, bits, hc);

    gemm_ff<<<dim3(128,2), 256, 0, stream>>>(hc, wtf + (size_t)l*DD*512, WF_b + l*DD, ffo);

    if (l == 0) ln_res2<1><<<MM/4, 256, 0, stream>>>(ffo, node, ln_g, ln_b, hout, hbf);
    else        ln_res2<0><<<MM/4, 256, 0, stream>>>(ffo, (const float*)hout,
                                                     ln_g + DD, ln_b + DD, hout, nullptr);
  }
}

// Round 14
// 297.097 us; speedup vs baseline: 1.0224x; 1.0021x over previous
//
#include <hip/hip_runtime.h>
#include <hip/hip_bf16.h>

#define BB 16
#define NN 1024
#define DD 256
#define FF_ 128
#define LL 2
#define RR 2
#define DF 384
#define MM (BB*NN)
#define NPROJ 1280
#define PK 768            // POUT row stride (Q:0..255, K0:256..511, K1:512..767)
#define CSC 0.09016844f   // (1/16) * log2(e), folded into WQ at prep

typedef __attribute__((ext_vector_type(8))) short s16x8;
typedef __attribute__((ext_vector_type(4))) float f32x4;
typedef __attribute__((ext_vector_type(16))) float f32x16;
typedef __attribute__((ext_vector_type(2))) unsigned int u32x2;
typedef __attribute__((ext_vector_type(4))) unsigned int u32x4;
typedef __attribute__((ext_vector_type(4))) unsigned short us16x4;

__device__ __forceinline__ unsigned short f2bf(float f){
  unsigned u = __builtin_bit_cast(unsigned, f);
  u += 0x7fff + ((u >> 16) & 1);
  return (unsigned short)(u >> 16);
}

__device__ __forceinline__ void gload16(const void* g, void* l){
  __builtin_amdgcn_global_load_lds(
      (const __attribute__((address_space(1))) unsigned int*)g,
      (__attribute__((address_space(3))) unsigned int*)l, 16, 0, 0);
}

#define MFMA16(a,b,c) __builtin_amdgcn_mfma_f32_16x16x32_bf16((a),(b),(c),0,0,0)
#define MFMA32(a,b,c) __builtin_amdgcn_mfma_f32_32x32x16_bf16((a),(b),(c),0,0,0)

// ---------------- one-shot prep: weights, biases, x1, hbf, adj bitmasks ----------------
#define PREP_WT   3840
#define PREP_WTF  1024
#define PREP_BALL 10
#define PREP_X1   16
#define PREP_H    2048
#define PREP_TOT  (PREP_WT+PREP_WTF+PREP_BALL+PREP_X1+PREP_H)
#define PREP_ADJ  8192
#define PREP_ALL  (PREP_TOT+PREP_ADJ)

__global__ __launch_bounds__(256) void prep(
    const float* __restrict__ node, const float* __restrict__ inx,
    const float* __restrict__ WQi_w, const float* __restrict__ WQi_b,
    const float* __restrict__ WQ_w, const float* __restrict__ WK_w,
    const float* __restrict__ WV_w, const float* __restrict__ WQ_b,
    const float* __restrict__ WK_b, const float* __restrict__ WV_b,
    const float* __restrict__ WF_w, const int* __restrict__ adj,
    unsigned short* __restrict__ wtall, unsigned short* __restrict__ wtf,
    float* __restrict__ ball, unsigned short* __restrict__ x1bf,
    unsigned short* __restrict__ hbf, unsigned long long* __restrict__ bits){
  int bid = blockIdx.x, t = threadIdx.x;
  if (bid < PREP_WT){
    int o = bid*256 + t;                       // < 2*1280*384
    int l = o / (NPROJ*DF); int oo = o - l*(NPROJ*DF);
    int n = oo / DF, k = oo - n*DF;
    const float* WQ = WQ_w + (size_t)l*DF*256;
    const float* WK = WK_w + (size_t)l*RR*DF*256;
    const float* WV = WV_w + (size_t)l*RR*DF*256;
    float v;
    if (n < 256)      v = WQ[(size_t)k*256 + n] * CSC;   // fold attn scale into Q
    else if (n < 768) v = WK[(size_t)((n-256)>>8)*(DF*256) + (size_t)k*256 + ((n-256)&255)];
    else              v = WV[(size_t)((n-768)>>8)*(DF*256) + (size_t)k*256 + ((n-768)&255)];
    wtall[o] = f2bf(v);
  } else if (bid < PREP_WT + PREP_WTF){
    int o = (bid - PREP_WT)*256 + t;           // < 2*512*256
    int l = o >> 17; int oo = o & 131071;
    int n = oo >> 9, k = oo & 511;
    wtf[o] = f2bf(WF_w[(size_t)l*512*256 + (size_t)k*256 + n]);
  } else if (bid < PREP_WT + PREP_WTF + PREP_BALL){
    int o = (bid - PREP_WT - PREP_WTF)*256 + t;
    if (o < 2*NPROJ){
      int l = o / NPROJ, n = o - l*NPROJ;
      float v = (n < 256) ? WQ_b[l*256 + n] * CSC
              : (n < 768) ? WK_b[(size_t)l*512 + (n-256)]
                          : WV_b[(size_t)l*512 + (n-768)];
      ball[o] = v;
    }
  } else if (bid < PREP_WT + PREP_WTF + PREP_BALL + PREP_X1){
    int o = (bid - PREP_WT - PREP_WTF - PREP_BALL)*256 + t;  // < 4096
    int l = o >> 11, bj = o & 2047;
    int b = bj >> 7, j = bj & 127;
    const float* w = WQi_w + (size_t)l*FF_*FF_;
    float s = WQi_b[l*FF_ + j];
    for (int i = 0; i < FF_; ++i) s += inx[b*FF_ + i] * w[i*FF_ + j];
    x1bf[o] = f2bf(s);
  } else if (bid < PREP_TOT){
    int o = (bid - (PREP_TOT - PREP_H))*256 + t;             // < 524288, 8 elems each
    const float4* src = (const float4*)node + (size_t)o*2;
    float4 a = src[0], c = src[1];
    uint4 pk;
    pk.x = (unsigned)f2bf(a.x) | ((unsigned)f2bf(a.y) << 16);
    pk.y = (unsigned)f2bf(a.z) | ((unsigned)f2bf(a.w) << 16);
    pk.z = (unsigned)f2bf(c.x) | ((unsigned)f2bf(c.y) << 16);
    pk.w = (unsigned)f2bf(c.z) | ((unsigned)f2bf(c.w) << 16);
    *(uint4*)(hbf + (size_t)o*8) = pk;
  } else {
    // adj -> bitmask (R,B,N, 16 x u64)
    int w = t >> 6, lane = t & 63;
    size_t row = (size_t)(bid - PREP_TOT) * 4 + w;
    const int* a = adj + row * NN;
    unsigned long long* brow = bits + row * 16;
    #pragma unroll
    for (int j = 0; j < 16; ++j){
      unsigned long long m = __ballot(a[j*64 + lane] != 0);
      if (lane == 0) brow[j] = m;
    }
  }
}

// ------------- big projection GEMM: A=concat(hbf,x1), N=1280, K=384 -------------
// counted-vmcnt split-barrier loop. bn<6: POUT. bn>=6: V transposed to vtall.
__global__ __launch_bounds__(256) void gemm_big(const unsigned short* __restrict__ hbf,
    const unsigned short* __restrict__ x1l, const unsigned short* __restrict__ Wt,
    const float* __restrict__ bias, unsigned short* __restrict__ POUT,
    unsigned short* __restrict__ vtall){
  __shared__ unsigned short As[2][128*32];
  __shared__ unsigned short Bs[2][128*32];
  int t = threadIdx.x, lane = t & 63, w = t >> 6;
  int wr = w >> 1, wc = w & 1, l15 = lane & 15, lhi = lane >> 4;
  int bm = blockIdx.x, bn = blockIdx.y, bb = bm >> 3;
  f32x4 acc[4][4];
  #pragma unroll
  for (int m = 0; m < 4; ++m)
    #pragma unroll
    for (int n = 0; n < 4; ++n) acc[m][n] = (f32x4){0.f,0.f,0.f,0.f};

  auto STAGE = [&](int bi, int kk){
    #pragma unroll
    for (int i = 0; i < 2; ++i){
      int base = w*2048 + i*1024;
      int off = base + lane*16;
      int row = off >> 6, cb = off & 63;
      const char* asrc = (kk < 8)
        ? (const char*)hbf + ((size_t)(bm*128 + row)*256 + kk*32)*2 + cb
        : (const char*)x1l + ((size_t)bb*128 + (kk-8)*32)*2 + cb;
      gload16(asrc, (char*)As[bi] + base);
      gload16((const char*)Wt + ((size_t)(bn*128 + row)*DF + kk*32)*2 + cb,
              (char*)Bs[bi] + base);
    }
  };

  STAGE(0, 0);
  for (int kk = 0; kk < 12; ++kk){
    int cur = kk & 1;
    if (kk + 1 < 12){
      STAGE(cur ^ 1, kk + 1);
      asm volatile("s_waitcnt vmcnt(4)" ::: "memory");
    } else {
      asm volatile("s_waitcnt vmcnt(0)" ::: "memory");
    }
    __builtin_amdgcn_s_barrier();
    __builtin_amdgcn_sched_barrier(0);
    s16x8 af[4], bfr[4];
    #pragma unroll
    for (int m = 0; m < 4; ++m) af[m]  = *(const s16x8*)&As[cur][(wr*64 + m*16 + l15)*32 + lhi*8];
    #pragma unroll
    for (int n = 0; n < 4; ++n) bfr[n] = *(const s16x8*)&Bs[cur][(wc*64 + n*16 + l15)*32 + lhi*8];
    __builtin_amdgcn_s_setprio(1);
    #pragma unroll
    for (int m = 0; m < 4; ++m)
      #pragma unroll
      for (int n = 0; n < 4; ++n)
        acc[m][n] = MFMA16(af[m], bfr[n], acc[m][n]);
    __builtin_amdgcn_s_setprio(0);
    __builtin_amdgcn_s_barrier();            // all reads of cur done -> overwrite safe
  }

  if (bn < 6){
    #pragma unroll
    for (int n = 0; n < 4; ++n){
      int gn = bn*128 + wc*64 + n*16 + l15;
      float bv = bias[gn];
      #pragma unroll
      for (int m = 0; m < 4; ++m){
        int gm = bm*128 + wr*64 + m*16 + lhi*4;
        #pragma unroll
        for (int i = 0; i < 4; ++i)
          POUT[(size_t)(gm + i)*PK + gn] = f2bf(acc[m][n][i] + bv);
      }
    }
  } else {
    #pragma unroll
    for (int n = 0; n < 4; ++n){
      int gn = bn*128 + wc*64 + n*16 + l15;
      float bv = bias[gn];
      int rv = gn - 768;
      int r = rv >> 8, d = rv & 255;
      #pragma unroll
      for (int m = 0; m < 4; ++m){
        int mb = (bm & 7)*128 + wr*64 + m*16 + lhi*4;
        us16x4 pk;
        #pragma unroll
        for (int i = 0; i < 4; ++i) pk[i] = f2bf(acc[m][n][i] + bv);
        *(us16x4*)(vtall + ((size_t)((r*16 + bb)*256 + d))*NN + mb) = pk;
      }
    }
  }
}

// ------------- flash attention v12: attn10 + conflict-free swizzles ----
// K tile [64 rows][512B], 5-bit XOR swizzle (row&31)<<4  -> QK reads conflict-free.
// V tile [128 pair-rows][256B] (pair p = d-rows {p, p+128}), 4-bit XOR (p&15)<<4
//   -> PV reads 2-way (free). grid 256 XCD-swizzled, block 512 = 4 qsubs x 2 dh.
__global__ __launch_bounds__(512, 1) void attn12(const unsigned short* __restrict__ P,
    const unsigned short* __restrict__ VT, const unsigned long long* __restrict__ bits,
    unsigned short* __restrict__ hc){
  __shared__ char smem[147456];

  int t = threadIdx.x, lane = t & 63, w = t >> 6;
  int h = lane >> 5, l31 = lane & 31;
  int qsub = w >> 1, dh = w & 1;          // q-subtile, d-half
  int F = blockIdx.x;
  int xcd = F & 7, j = F >> 3;
  int qt = j & 7;
  int gidx = xcd*4 + (j >> 3);
  int b = gidx & 15, r = gidx >> 4;

  size_t kcol = 256 + (size_t)r*256;
  const unsigned short* Vb = VT + ((size_t)(r*16 + b))*256*NN;
  int qrow = qt*128 + qsub*32 + l31;

  // Q in registers: 16 B-operand frags (lane = q-col, full D), pre-scaled by CSC
  s16x8 qf[16];
  {
    const unsigned short* qp = P + ((size_t)(b*NN + qrow))*PK + h*8;
    #pragma unroll
    for (int d_ = 0; d_ < 16; ++d_) qf[d_] = *(const s16x8*)(qp + d_*16);
  }

  // stage all masks for this block's 128 q-rows into LDS [kt][row]
  {
    const unsigned long long* bb0 = bits + ((size_t)(r*BB + b)*NN + qt*128)*16;
    unsigned long long* ml = (unsigned long long*)(smem + 131072);
    #pragma unroll
    for (int i = 0; i < 4; ++i){
      int idx = t + i*512;                // < 2048
      int kt = idx >> 7, row = idx & 127;
      ml[kt*128 + row] = bb0[(size_t)row*16 + kt];
    }
  }

  f32x16 acc[4];                           // d-half: d in [dh*128, dh*128+128)
  #pragma unroll
  for (int dt = 0; dt < 4; ++dt)
    #pragma unroll
    for (int i = 0; i < 16; ++i) acc[dt][i] = 0.f;
  float mrow = -3e38f, lrow = 0.f;

  // buf base = buf*65536; K at +0 (32KB), V at +32768 (32KB, paired 256B rows)
  auto STAGE = [&](int buf, int kt){
    char* base = smem + buf*65536;
    #pragma unroll
    for (int i = 0; i < 4; ++i){
      int o = i*8192 + t*16;              // [0,32768)
      int kr = o >> 9, cb = o & 511;
      int lcb = cb ^ ((kr & 31) << 4);    // 5-bit swizzle
      gload16((const char*)P + ((size_t)(b*NN + kt*64 + kr)*PK + kcol)*2 + lcb,
              base + o);
    }
    #pragma unroll
    for (int i = 0; i < 4; ++i){
      int o = i*8192 + t*16;              // [0,32768)
      int p = o >> 8, rem = o & 255;
      int lrem = rem ^ ((p & 15) << 4);   // 4-bit swizzle within 256B pair-row
      int drow = p + (lrem >> 7)*128, col = lrem & 127;
      gload16((const char*)Vb + ((size_t)drow*NN + kt*64)*2 + col,
              base + 32768 + o);
    }
  };

  STAGE(0, 0);
  __syncthreads();                         // drains Q/mask reads + ds_writes + stage0

  for (int kt = 0; kt < 16; ++kt){
    int cur = kt & 1;
    if (kt + 1 < 16){
      STAGE(cur ^ 1, kt + 1);
      asm volatile("s_waitcnt vmcnt(8)" ::: "memory");
    } else {
      asm volatile("s_waitcnt vmcnt(0)" ::: "memory");
    }
    __builtin_amdgcn_s_barrier();          // cur tiles ready in all waves
    __builtin_amdgcn_sched_barrier(0);

    unsigned long long mwv64 = *(const unsigned long long*)
        (smem + 131072 + kt*1024 + (qsub*32 + l31)*8);

    const char* Kc = smem + cur*65536;
    const char* Vc = smem + cur*65536 + 32768;

    // QK: dual independent chains over both 32-k subtiles, D=256
    f32x16 st0, st1;
    #pragma unroll
    for (int i = 0; i < 16; ++i){ st0[i] = 0.f; st1[i] = 0.f; }
    int swzk = l31 << 4;                   // (row&31)<<4; rows l31 and 32+l31 equal
    const char* kb0 = Kc + l31*512;
    const char* kb1 = Kc + (32 + l31)*512;
    #pragma unroll
    for (int d_ = 0; d_ < 16; ++d_){
      int co = (d_*32 + h*16) ^ swzk;
      s16x8 kf0 = *(const s16x8*)(kb0 + co);
      s16x8 kf1 = *(const s16x8*)(kb1 + co);
      st0 = MFMA32(kf0, qf[d_], st0);
      st1 = MFMA32(kf1, qf[d_], st1);
    }

    // per-subtile: mask -> online softmax -> pack -> PV
    auto PROC = [&](f32x16 st, unsigned mw, int vcol){
      #pragma unroll
      for (int rr = 0; rr < 16; ++rr){
        int kb = (rr & 3) + 8*(rr >> 2) + 4*h;
        st[rr] = ((mw >> kb) & 1u) ? st[rr] : -1.443e9f;
      }
      float t8[8];
      #pragma unroll
      for (int p = 0; p < 8; ++p) t8[p] = fmaxf(st[p], st[p+8]);
      #pragma unroll
      for (int p = 0; p < 4; ++p) t8[p] = fmaxf(t8[p], t8[p+4]);
      float tm = fmaxf(fmaxf(t8[0], t8[1]), fmaxf(t8[2], t8[3]));
      tm = fmaxf(tm, __shfl_xor(tm, 32));
      if (tm > mrow + 10.f){               // defer-max; per-lane scalar rescale
        float f = exp2f(mrow - tm);
        mrow = tm;
        lrow *= f;
        #pragma unroll
        for (int dt = 0; dt < 4; ++dt)
          #pragma unroll
          for (int i = 0; i < 16; ++i) acc[dt][i] *= f;
      }
      #pragma unroll
      for (int rr = 0; rr < 16; ++rr) st[rr] = exp2f(st[rr] - mrow);
      #pragma unroll
      for (int p = 0; p < 8; ++p) t8[p] = st[p] + st[p+8];
      #pragma unroll
      for (int p = 0; p < 4; ++p) t8[p] = t8[p] + t8[p+4];
      float rs = (t8[0] + t8[1]) + (t8[2] + t8[3]);
      rs += __shfl_xor(rs, 32);
      lrow += rs;

      unsigned pk[8];
      #pragma unroll
      for (int p = 0; p < 8; ++p){
        unsigned rpk;
        float lo = st[p*2], hi = st[p*2+1];
        asm("v_cvt_pk_bf16_f32 %0, %1, %2" : "=v"(rpk) : "v"(lo), "v"(hi));
        pk[p] = rpk;
      }
      unsigned sA = h ? pk[0] : pk[2], sB = h ? pk[1] : pk[3];
      unsigned sC = h ? pk[4] : pk[6], sD = h ? pk[5] : pk[7];
      unsigned rxA = (unsigned)__shfl_xor((int)sA, 32);
      unsigned rxB = (unsigned)__shfl_xor((int)sB, 32);
      unsigned rxC = (unsigned)__shfl_xor((int)sC, 32);
      unsigned rxD = (unsigned)__shfl_xor((int)sD, 32);
      u32x4 pv0, pv1;
      pv0[0] = h ? rxA : pk[0]; pv0[1] = h ? rxB : pk[1];
      pv0[2] = h ? pk[2] : rxA; pv0[3] = h ? pk[3] : rxB;
      pv1[0] = h ? rxC : pk[4]; pv1[1] = h ? rxD : pk[5];
      pv1[2] = h ? pk[6] : rxC; pv1[3] = h ? pk[7] : rxD;
      s16x8 pa0 = __builtin_bit_cast(s16x8, pv0);
      s16x8 pa1 = __builtin_bit_cast(s16x8, pv1);

      // PV swapped on paired-row V layout: pair p = dt*32+l31, col = dh*128 + k*32 + h*16
      #pragma unroll
      for (int dt = 0; dt < 4; ++dt){
        int p = dt*32 + l31;
        int swzv = (p & 15) << 4;
        const char* vbase = Vc + p*256;
        s16x8 vf0 = *(const s16x8*)(vbase + ((dh*128 + vcol + h*16) ^ swzv));
        acc[dt] = MFMA32(vf0, pa0, acc[dt]);
        s16x8 vf1 = *(const s16x8*)(vbase + ((dh*128 + vcol + 32 + h*16) ^ swzv));
        acc[dt] = MFMA32(vf1, pa1, acc[dt]);
      }
    };
    PROC(st0, (unsigned)mwv64, 0);
    PROC(st1, (unsigned)(mwv64 >> 32), 64);

    __builtin_amdgcn_s_barrier();          // all reads of cur done -> overwrite safe
  }

  // epilogue: per-lane normalize + direct store
  float inv = 1.f / lrow;
  unsigned short* hrow = hc + ((size_t)(b*NN + qrow))*(RR*DD) + r*DD;
  #pragma unroll
  for (int dt = 0; dt < 4; ++dt){
    #pragma unroll
    for (int g = 0; g < 4; ++g){
      float a0 = acc[dt][g*4+0]*inv, a1 = acc[dt][g*4+1]*inv;
      float a2 = acc[dt][g*4+2]*inv, a3 = acc[dt][g*4+3]*inv;
      unsigned r0, r1;
      asm("v_cvt_pk_bf16_f32 %0, %1, %2" : "=v"(r0) : "v"(a0), "v"(a1));
      asm("v_cvt_pk_bf16_f32 %0, %1, %2" : "=v"(r1) : "v"(a2), "v"(a3));
      int d = dh*128 + dt*32 + 8*g + 4*h;
      u32x2 pv; pv[0] = r0; pv[1] = r1;
      *(u32x2*)(hrow + d) = pv;
    }
  }
}

// ------------- FF GEMM: A=hc (K=512), out f32, counted-vmcnt loop -------------
__global__ __launch_bounds__(256) void gemm_ff(const unsigned short* __restrict__ A,
    const unsigned short* __restrict__ Wt, const float* __restrict__ bias,
    float* __restrict__ out){
  __shared__ unsigned short As[2][128*32];
  __shared__ unsigned short Bs[2][128*32];
  int t = threadIdx.x, lane = t & 63, w = t >> 6;
  int wr = w >> 1, wc = w & 1, l15 = lane & 15, lhi = lane >> 4;
  int bm = blockIdx.x, bn = blockIdx.y;
  f32x4 acc[4][4];
  #pragma unroll
  for (int m = 0; m < 4; ++m)
    #pragma unroll
    for (int n = 0; n < 4; ++n) acc[m][n] = (f32x4){0.f,0.f,0.f,0.f};

  auto STAGE = [&](int bi, int kk){
    #pragma unroll
    for (int i = 0; i < 2; ++i){
      int base = w*2048 + i*1024;
      int off = base + lane*16;
      int row = off >> 6, cb = off & 63;
      gload16((const char*)A  + ((size_t)(bm*128 + row)*512 + kk*32)*2 + cb,
              (char*)As[bi] + base);
      gload16((const char*)Wt + ((size_t)(bn*128 + row)*512 + kk*32)*2 + cb,
              (char*)Bs[bi] + base);
    }
  };

  STAGE(0, 0);
  for (int kk = 0; kk < 16; ++kk){
    int cur = kk & 1;
    if (kk + 1 < 16){
      STAGE(cur ^ 1, kk + 1);
      asm volatile("s_waitcnt vmcnt(4)" ::: "memory");
    } else {
      asm volatile("s_waitcnt vmcnt(0)" ::: "memory");
    }
    __builtin_amdgcn_s_barrier();
    __builtin_amdgcn_sched_barrier(0);
    s16x8 af[4], bfr[4];
    #pragma unroll
    for (int m = 0; m < 4; ++m) af[m]  = *(const s16x8*)&As[cur][(wr*64 + m*16 + l15)*32 + lhi*8];
    #pragma unroll
    for (int n = 0; n < 4; ++n) bfr[n] = *(const s16x8*)&Bs[cur][(wc*64 + n*16 + l15)*32 + lhi*8];
    __builtin_amdgcn_s_setprio(1);
    #pragma unroll
    for (int m = 0; m < 4; ++m)
      #pragma unroll
      for (int n = 0; n < 4; ++n)
        acc[m][n] = MFMA16(af[m], bfr[n], acc[m][n]);
    __builtin_amdgcn_s_setprio(0);
    __builtin_amdgcn_s_barrier();
  }

  #pragma unroll
  for (int n = 0; n < 4; ++n){
    int gn = bn*128 + wc*64 + n*16 + l15;
    float bv = bias[gn];
    #pragma unroll
    for (int m = 0; m < 4; ++m){
      int gm = bm*128 + wr*64 + m*16 + lhi*4;
      #pragma unroll
      for (int i = 0; i < 4; ++i)
        out[(size_t)(gm + i)*DD + gn] = acc[m][n][i] + bv;
    }
  }
}

// ------------- relu + residual + layernorm (+ optional hbf write) -------------
template<int WRITEH>
__global__ __launch_bounds__(256) void ln_res2(const float* __restrict__ ff,
    const float* __restrict__ hin, const float* __restrict__ g,
    const float* __restrict__ bv, float* __restrict__ hout,
    unsigned short* __restrict__ hbf){
  int w = threadIdx.x >> 6, lane = threadIdx.x & 63;
  size_t row = (size_t)blockIdx.x * 4 + w;
  f32x4 fv = *(const f32x4*)(ff  + row*DD + lane*4);
  f32x4 hv = *(const f32x4*)(hin + row*DD + lane*4);
  float x[4], s = 0.f, ss = 0.f;
  #pragma unroll
  for (int j = 0; j < 4; ++j){ x[j] = fmaxf(fv[j], 0.f) + hv[j]; s += x[j]; ss += x[j]*x[j]; }
  #pragma unroll
  for (int xm = 1; xm < 64; xm <<= 1){ s += __shfl_xor(s, xm); ss += __shfl_xor(ss, xm); }
  float mu = s * (1.f/256.f);
  float var = ss * (1.f/256.f) - mu*mu;
  float rstd = rsqrtf(var + 1e-5f);
  f32x4 o;
  #pragma unroll
  for (int j = 0; j < 4; ++j){ int c = lane*4 + j; o[j] = (x[j]-mu)*rstd*g[c] + bv[c]; }
  *(f32x4*)(hout + row*DD + lane*4) = o;
  if (WRITEH){
    uint2 pv;
    pv.x = (unsigned)f2bf(o[0]) | ((unsigned)f2bf(o[1]) << 16);
    pv.y = (unsigned)f2bf(o[2]) | ((unsigned)f2bf(o[3]) << 16);
    *(uint2*)(hbf + row*DD + lane*4) = pv;
  }
}

extern "C" void kernel_launch(void* const* d_in, const int* in_sizes, int n_in,
                              void* d_out, int out_size, void* d_ws, size_t ws_size,
                              hipStream_t stream){
  (void)in_sizes; (void)n_in; (void)out_size; (void)ws_size;
  const float* node  = (const float*)d_in[0];
  const float* inx   = (const float*)d_in[1];
  const int*   adj   = (const int*)d_in[2];
  const float* WQi_w = (const float*)d_in[3];
  const float* WQi_b = (const float*)d_in[4];
  const float* WQ_w  = (const float*)d_in[5];
  const float* WQ_b  = (const float*)d_in[6];
  const float* WK_w  = (const float*)d_in[7];
  const float* WK_b  = (const float*)d_in[8];
  const float* WV_w  = (const float*)d_in[9];
  const float* WV_b  = (const float*)d_in[10];
  const float* WF_w  = (const float*)d_in[11];
  const float* WF_b  = (const float*)d_in[12];
  const float* ln_g  = (const float*)d_in[13];
  const float* ln_b  = (const float*)d_in[14];
  float* hout = (float*)d_out;

  char* wsp = (char*)d_ws;
  auto alloc = [&](size_t n){ char* p = wsp; wsp += (n + 255) & ~(size_t)255; return p; };
  unsigned long long* bits = (unsigned long long*)alloc((size_t)RR*BB*NN*16*8);
  unsigned short* wtall = (unsigned short*)alloc((size_t)2*NPROJ*DF*2);
  unsigned short* wtf   = (unsigned short*)alloc((size_t)2*DD*512*2);
  float*          ball  = (float*)alloc((size_t)2*NPROJ*4);
  unsigned short* x1bf  = (unsigned short*)alloc((size_t)2*BB*FF_*2);
  unsigned short* hbf   = (unsigned short*)alloc((size_t)MM*DD*2);
  unsigned short* POUT  = (unsigned short*)alloc((size_t)MM*PK*2);
  unsigned short* vtall = (unsigned short*)alloc((size_t)RR*BB*DD*NN*2);
  unsigned short* hc    = (unsigned short*)alloc((size_t)MM*512*2);
  float*          ffo   = (float*)alloc((size_t)MM*DD*4);

  prep<<<PREP_ALL, 256, 0, stream>>>(node, inx, WQi_w, WQi_b, WQ_w, WK_w, WV_w,
                                     WQ_b, WK_b, WV_b, WF_w, adj,
                                     wtall, wtf, ball, x1bf, hbf, bits);

  for (int l = 0; l < LL; ++l){
    gemm_big<<<dim3(128,10), 256, 0, stream>>>(hbf, x1bf + (size_t)l*BB*FF_,
        wtall + (size_t)l*NPROJ*DF, ball + (size_t)l*NPROJ, POUT, vtall);

    attn12<<<256, 512, 0, stream>>>(POUT, vtall, bits, hc);

    gemm_ff<<<dim3(128,2), 256, 0, stream>>>(hc, wtf + (size_t)l*DD*512, WF_b + l*DD, ffo);

    if (l == 0) ln_res2<1><<<MM/4, 256, 0, stream>>>(ffo, node, ln_g, ln_b, hout, hbf);
    else        ln_res2<0><<<MM/4, 256, 0, stream>>>(ffo, (const float*)hout,
                                                     ln_g + DD, ln_b + DD, hout, nullptr);
  }
}